// Round 1
// baseline (722.602 us; speedup 1.0000x reference)
//
#include <hip/hip_runtime.h>
#include <hip/hip_bf16.h>
#include <hip/hip_fp16.h>

typedef __bf16 bf16x8 __attribute__((ext_vector_type(8)));
typedef float f32x4 __attribute__((ext_vector_type(4)));

constexpr int NUM_G = 16384;   // static segment count
constexpr int DIM = 128;       // D == HS == 128
constexpr int CHUNK = 64;      // rows per LDS staging chunk
constexpr int GRID1 = 768;     // persistent blocks: 3 blocks/CU * 256 CUs

// Kernel 0: seg[g] = first index v with batch[v] >= g (batch is sorted). seg[NUM_G] = V.
__global__ void seg_starts_kernel(const int* __restrict__ batch, int* __restrict__ seg, int V) {
    int v = blockIdx.x * blockDim.x + threadIdx.x;
    if (v >= V) return;
    int b1 = batch[v];
    int b0 = (v == 0) ? -1 : batch[v - 1];
    for (int g = b0 + 1; g <= b1; ++g) seg[g] = v;
    if (v == V - 1)
        for (int g = b1 + 1; g <= NUM_G; ++g) seg[g] = V;
}

// Fused: project (bf16 MFMA) -> tanh -> score -> segment softmax -> weighted sum.
// Each block persists over graphs g = bid, bid+GRID1, ... W_proj fragments live in
// VGPRs for the whole block (wave w owns n-tiles [4*(w&1), 4*(w&1)+4), m-rows
// [32*(w>>1), 32*(w>>1)+32)). H rows staged to LDS as bf16, XOR-swizzled
// (chunk ^ (row&15)) so ds_read_b128 A-fragment reads are at the free 2-way level.
__launch_bounds__(256, 3)
__global__ void attn_agg_kernel(const float* __restrict__ Hm,
                                const float* __restrict__ Wp,
                                const float* __restrict__ bp,
                                const float* __restrict__ wsc,
                                const int* __restrict__ seg,
                                float* __restrict__ out) {
    __shared__ __align__(16) __bf16 Hs[CHUNK * DIM];  // 16 KB, swizzled
    __shared__ float e_part[2][CHUNK];                // per-nhalf partial e
    __shared__ float alpha_s[CHUNK];                  // exp(e) per row
    __shared__ float red[4];                          // per-wave reduce scratch

    const int t = threadIdx.x;
    const int lane = t & 63;
    const int wave = t >> 6;
    const int l15 = lane & 15;
    const int lq = lane >> 4;      // 0..3
    const int mgrp = wave >> 1;    // 0: rows 0-31, 1: rows 32-63
    const int nhalf = wave & 1;    // 0: n-tiles 0-3, 1: n-tiles 4-7

    // Preload W_proj B-fragments (bf16) + per-lane bias/score, once per block.
    // B[n][k]: lane holds n = lane&15 (+16*ntile), k = (lane>>4)*8 + j  (+32*kstep)
    bf16x8 bfrag[4][4];
    float bias_n[4], wsc_n[4];
#pragma unroll
    for (int nt = 0; nt < 4; ++nt) {
        int n_g = (nhalf * 4 + nt) * 16 + l15;
        bias_n[nt] = bp[n_g];
        wsc_n[nt] = wsc[n_g];
#pragma unroll
        for (int ks = 0; ks < 4; ++ks) {
            const float* src = Wp + n_g * DIM + ks * 32 + lq * 8;
            f32x4 w0 = *(const f32x4*)src;
            f32x4 w1 = *(const f32x4*)(src + 4);
            bf16x8 f;
            f[0] = (__bf16)w0[0]; f[1] = (__bf16)w0[1]; f[2] = (__bf16)w0[2]; f[3] = (__bf16)w0[3];
            f[4] = (__bf16)w1[0]; f[5] = (__bf16)w1[1]; f[6] = (__bf16)w1[2]; f[7] = (__bf16)w1[3];
            bfrag[nt][ks] = f;
        }
    }

    for (int g = blockIdx.x; g < NUM_G; g += GRID1) {
        int v0 = seg[g];
        int n = seg[g + 1] - v0;
        float acc = 0.f;    // thread t<128 owns output column t
        float lsum = 0.f;   // softmax denominator (no max-shift needed: |e| <~ 15)

        for (int r0 = 0; r0 < n; r0 += CHUNK) {
            int c = min(CHUNK, n - r0);
            __syncthreads();  // previous chunk/graph readers done before overwrite

            // Stage c rows of H -> LDS bf16, fully coalesced (thread t covers byte
            // offset t*32 of the contiguous [c x 128] fp32 block).
            for (int i = t; i < c * 16; i += 256) {
                int row = i >> 4, ch = i & 15;
                const float* src = Hm + (size_t)(v0 + r0 + row) * DIM + ch * 8;
                f32x4 a0 = *(const f32x4*)src;
                f32x4 a1 = *(const f32x4*)(src + 4);
                bf16x8 hv;
                hv[0] = (__bf16)a0[0]; hv[1] = (__bf16)a0[1]; hv[2] = (__bf16)a0[2]; hv[3] = (__bf16)a0[3];
                hv[4] = (__bf16)a1[0]; hv[5] = (__bf16)a1[1]; hv[6] = (__bf16)a1[2]; hv[7] = (__bf16)a1[3];
                int chs = ch ^ (row & 15);
                *(bf16x8*)&Hs[row * DIM + chs * 8] = hv;
            }
            __syncthreads();

            // Projection via MFMA. Rows >= c compute garbage e (MFMA row-independent;
            // never read). 2 m-tiles per wave.
#pragma unroll
            for (int mt = 0; mt < 2; ++mt) {
                int mtile = mgrp * 2 + mt;
                int arow = mtile * 16 + l15;
                bf16x8 afrag[4];
#pragma unroll
                for (int ks = 0; ks < 4; ++ks) {
                    int chs = (ks * 4 + lq) ^ l15;
                    afrag[ks] = *(const bf16x8*)&Hs[arow * DIM + chs * 8];
                }
                float epl[4] = {0.f, 0.f, 0.f, 0.f};
#pragma unroll
                for (int nt = 0; nt < 4; ++nt) {
                    f32x4 dacc = {0.f, 0.f, 0.f, 0.f};
#pragma unroll
                    for (int ks = 0; ks < 4; ++ks)
                        dacc = __builtin_amdgcn_mfma_f32_16x16x32_bf16(afrag[ks], bfrag[nt][ks], dacc, 0, 0, 0);
                    // C/D layout: col = lane&15 (= n within tile), row = lq*4 + reg
#pragma unroll
                    for (int r = 0; r < 4; ++r) {
                        float x = dacc[r] + bias_n[nt];
                        float ex = __expf(2.f * x);                       // v_exp_f32
                        float th = 1.f - 2.f * __builtin_amdgcn_rcpf(ex + 1.f);  // tanh, NaN-free
                        epl[r] += th * wsc_n[nt];
                    }
                }
                // Reduce over the 16 columns this wave holds (lanes differing in bits 0-3)
#pragma unroll
                for (int m = 1; m < 16; m <<= 1)
#pragma unroll
                    for (int r = 0; r < 4; ++r)
                        epl[r] += __shfl_xor(epl[r], m, 64);
                if (l15 == 0)
#pragma unroll
                    for (int r = 0; r < 4; ++r)
                        e_part[nhalf][mtile * 16 + lq * 4 + r] = epl[r];
            }
            __syncthreads();

            // Combine halves, exp, chunk denominator
            float pv = 0.f;
            if (t < c) {
                float ev = e_part[0][t] + e_part[1][t];
                float p = __expf(ev);
                alpha_s[t] = p;
                pv = p;
            }
#pragma unroll
            for (int m = 1; m < 64; m <<= 1) pv += __shfl_xor(pv, m, 64);
            if (lane == 0) red[wave] = pv;
            __syncthreads();
            lsum += red[0] + red[1] + red[2] + red[3];

            // Weighted sum: thread t<128 owns column t; alpha_s reads are broadcast,
            // Hs bf16 reads are 2-lanes-per-bank (free).
            if (t < 128) {
                int dch = t >> 3, doff = t & 7;
                int r = 0;
                for (; r + 4 <= c; r += 4) {
                    float p0 = alpha_s[r],     p1 = alpha_s[r + 1];
                    float p2 = alpha_s[r + 2], p3 = alpha_s[r + 3];
                    float h0 = (float)Hs[(r)     * DIM + ((dch ^ ((r)     & 15)) * 8) + doff];
                    float h1 = (float)Hs[(r + 1) * DIM + ((dch ^ ((r + 1) & 15)) * 8) + doff];
                    float h2 = (float)Hs[(r + 2) * DIM + ((dch ^ ((r + 2) & 15)) * 8) + doff];
                    float h3 = (float)Hs[(r + 3) * DIM + ((dch ^ ((r + 3) & 15)) * 8) + doff];
                    acc += p0 * h0 + p1 * h1 + p2 * h2 + p3 * h3;
                }
                for (; r < c; ++r)
                    acc += alpha_s[r] * (float)Hs[r * DIM + ((dch ^ (r & 15)) * 8) + doff];
            }
        }

        if (t < 128)
            out[(size_t)g * DIM + t] = acc / fmaxf(lsum, 1e-12f);
        // n == 0: loop skipped, acc = lsum = 0 -> out = 0, matching segment_sum on
        // empty segments (and every output element is written each launch).
    }
}

extern "C" void kernel_launch(void* const* d_in, const int* in_sizes, int n_in,
                              void* d_out, int out_size, void* d_ws, size_t ws_size,
                              hipStream_t stream) {
    const float* Hm  = (const float*)d_in[0];
    const int* batch = (const int*)d_in[1];   // int32 per harness convention
    const float* Wp  = (const float*)d_in[2];
    const float* bp  = (const float*)d_in[3];
    const float* wsc = (const float*)d_in[4];
    float* out = (float*)d_out;
    int* seg = (int*)d_ws;                    // (NUM_G+1) ints = 64 KB scratch
    int V = in_sizes[1];

    seg_starts_kernel<<<(V + 255) / 256, 256, 0, stream>>>(batch, seg, V);
    attn_agg_kernel<<<GRID1, 256, 0, stream>>>(Hm, Wp, bp, wsc, seg, out);
}